// Round 1
// baseline (884.392 us; speedup 1.0000x reference)
//
#include <hip/hip_runtime.h>
#include <math.h>

// MHA: B=2, H=16, S=2048, D=64, DM=1024
// Pipeline: [1] QKV proj (f16 MFMA) -> q,k,v f16 [B,H,S,D]
//           [2] transpose V -> vt [B,H,D,S]
//           [3] flash attention -> o f16 [B,S,DM]
//           [4] out proj -> fp32 d_out
//
// MFMA 16x16x32 f16 layouts (verified per guide §3):
//   A-frag: lane holds A[m=lane&15][k=(lane>>4)*8 + j], j=0..7
//   B-frag: lane holds B[k=(lane>>4)*8 + j][n=lane&15]
//   C/D:    lane reg r holds D[row=(lane>>4)*4 + r][col=lane&15]

typedef _Float16 h8 __attribute__((ext_vector_type(8)));
typedef float f4 __attribute__((ext_vector_type(4)));

#define S_LEN 2048
#define DM 1024
#define NH 16
#define HD 64

// ---------------------------------------------------------------------------
// Kernel 1: QKV projection.  C[m,n] = sum_k X[m,k]*W[n,k] + b1[n] + b2[n]
// 128x128 tile, BK=32, 4 waves (2x2, 64x64 each). Writes f16 [B,H,S,D].
// LDS row stride 56 f16 = 112B (mult of 16 for ds_read_b128; 28-dword stride
// -> 2-way bank aliasing = free).
// ---------------------------------------------------------------------------
__global__ __launch_bounds__(256, 2) void qkv_proj_kernel(
    const float* __restrict__ Xq, const float* __restrict__ Xk, const float* __restrict__ Xv,
    const float* __restrict__ Wq, const float* __restrict__ Wk, const float* __restrict__ Wv,
    const float* __restrict__ bq, const float* __restrict__ bk, const float* __restrict__ bv,
    const float* __restrict__ bq2, const float* __restrict__ bk2, const float* __restrict__ bv2,
    _Float16* __restrict__ oq, _Float16* __restrict__ okk, _Float16* __restrict__ ov)
{
    const int z = blockIdx.z;
    const float* X  = (z == 0) ? Xq  : (z == 1) ? Xk  : Xv;
    const float* W  = (z == 0) ? Wq  : (z == 1) ? Wk  : Wv;
    const float* b1 = (z == 0) ? bq  : (z == 1) ? bk  : bv;
    const float* b2 = (z == 0) ? bq2 : (z == 1) ? bk2 : bv2;
    _Float16* outp  = (z == 0) ? oq  : (z == 1) ? okk : ov;

    __shared__ _Float16 As[128][56];
    __shared__ _Float16 Bs[128][56];

    const int tid  = threadIdx.x;
    const int lane = tid & 63;
    const int wave = tid >> 6;
    const int l16  = lane & 15;
    const int g    = lane >> 4;
    const int wm   = (wave >> 1) * 64;
    const int wn   = (wave & 1) * 64;
    const int m0   = blockIdx.x * 128;
    const int n0   = blockIdx.y * 128;

    f4 acc[4][4] = {};

    for (int k0 = 0; k0 < 1024; k0 += 32) {
        __syncthreads();  // prior iteration's frag reads done before overwrite
        #pragma unroll
        for (int r = 0; r < 4; ++r) {
            int f = tid + 256 * r;          // 1024 float4 units per 128x32 tile
            int row = f >> 3;
            int c4  = (f & 7) * 4;
            f4 xa = *(const f4*)(X + (size_t)(m0 + row) * 1024 + k0 + c4);
            f4 xb = *(const f4*)(W + (size_t)(n0 + row) * 1024 + k0 + c4);
            As[row][c4 + 0] = (_Float16)xa.x; As[row][c4 + 1] = (_Float16)xa.y;
            As[row][c4 + 2] = (_Float16)xa.z; As[row][c4 + 3] = (_Float16)xa.w;
            Bs[row][c4 + 0] = (_Float16)xb.x; Bs[row][c4 + 1] = (_Float16)xb.y;
            Bs[row][c4 + 2] = (_Float16)xb.z; Bs[row][c4 + 3] = (_Float16)xb.w;
        }
        __syncthreads();

        h8 af[4], bf[4];
        #pragma unroll
        for (int i = 0; i < 4; ++i) af[i] = *(const h8*)&As[wm + i * 16 + l16][g * 8];
        #pragma unroll
        for (int j = 0; j < 4; ++j) bf[j] = *(const h8*)&Bs[wn + j * 16 + l16][g * 8];
        #pragma unroll
        for (int i = 0; i < 4; ++i)
            #pragma unroll
            for (int j = 0; j < 4; ++j)
                acc[i][j] = __builtin_amdgcn_mfma_f32_16x16x32_f16(af[i], bf[j], acc[i][j], 0, 0, 0);
    }

    // epilogue: bias add, write f16 head-split [B,H,S,D]
    #pragma unroll
    for (int i = 0; i < 4; ++i)
        #pragma unroll
        for (int j = 0; j < 4; ++j)
            #pragma unroll
            for (int r = 0; r < 4; ++r) {
                int gm = m0 + wm + i * 16 + g * 4 + r;   // b*S + s
                int gn = n0 + wn + j * 16 + l16;         // h*64 + d
                float val = acc[i][j][r] + b1[gn] + b2[gn];
                int b = gm >> 11, s = gm & 2047;
                int h = gn >> 6,  d = gn & 63;
                outp[(((size_t)(b * NH + h) * S_LEN + s) << 6) + d] = (_Float16)val;
            }
}

// ---------------------------------------------------------------------------
// Kernel 2: V transpose  vt[bh][d][s] = v[bh][s][d]   (64x64 tiles)
// ---------------------------------------------------------------------------
__global__ __launch_bounds__(256) void transpose_v_kernel(
    const _Float16* __restrict__ v, _Float16* __restrict__ vt)
{
    const int bh = blockIdx.x;
    const int s0 = blockIdx.y * 64;
    __shared__ _Float16 t[64][65];
    const int tid = threadIdx.x;

    #pragma unroll
    for (int r = 0; r < 2; ++r) {
        int u = tid + 256 * r;           // 512 h8 units
        int row = u >> 3, c8 = (u & 7) * 8;
        h8 hv = *(const h8*)(v + ((size_t)bh * S_LEN + s0 + row) * 64 + c8);
        #pragma unroll
        for (int e = 0; e < 8; ++e) t[row][c8 + e] = hv[e];
    }
    __syncthreads();
    #pragma unroll
    for (int r = 0; r < 2; ++r) {
        int u = tid + 256 * r;
        int d = u >> 3, s8 = (u & 7) * 8;
        h8 hv;
        #pragma unroll
        for (int e = 0; e < 8; ++e) hv[e] = t[s8 + e][d];
        *(h8*)(vt + ((size_t)bh * 64 + d) * S_LEN + s0 + s8) = hv;
    }
}

// ---------------------------------------------------------------------------
// Kernel 3: flash attention. Block = (bh, 128 q-rows), 4 waves; wave w owns
// q-rows [w*32, w*32+32) x full tile width -> softmax stays within a wave.
// K-tile = 64. Online softmax (m,l per row in regs), P via LDS round-trip.
// LDS ~54 KB -> 2 blocks/CU.
// ---------------------------------------------------------------------------
__global__ __launch_bounds__(256, 2) void attn_kernel(
    const _Float16* __restrict__ q_ws, const _Float16* __restrict__ k_ws,
    const _Float16* __restrict__ vt_ws, const int* __restrict__ mask,
    _Float16* __restrict__ o_ws)
{
    const int tid  = threadIdx.x;
    const int lane = tid & 63;
    const int wave = tid >> 6;
    const int g    = lane >> 4;
    const int l16  = lane & 15;
    const int qt   = blockIdx.x;
    const int bh   = blockIdx.y;
    const int q0   = qt * 128;

    __shared__ _Float16 Qs[128][72];  // stride 72 f16 = 144B (16B mult)
    __shared__ _Float16 Ks[64][72];
    __shared__ _Float16 Vs[64][72];   // [d][s] (transposed V tile)
    __shared__ _Float16 Ps[128][72];

    // stage Q once
    #pragma unroll
    for (int r = 0; r < 4; ++r) {
        int u = tid + 256 * r;           // 1024 h8 units (128x64)
        int row = u >> 3, c8 = (u & 7) * 8;
        *(h8*)&Qs[row][c8] = *(const h8*)(q_ws + ((size_t)bh * S_LEN + q0 + row) * 64 + c8);
    }
    __syncthreads();

    h8 qf[2][2];
    #pragma unroll
    for (int i = 0; i < 2; ++i)
        #pragma unroll
        for (int ks = 0; ks < 2; ++ks)
            qf[i][ks] = *(const h8*)&Qs[wave * 32 + i * 16 + l16][ks * 32 + g * 8];

    f4 oacc[2][4] = {};
    float m_run[2][4], l_run[2][4];
    #pragma unroll
    for (int i = 0; i < 2; ++i)
        #pragma unroll
        for (int r = 0; r < 4; ++r) { m_run[i][r] = -INFINITY; l_run[i][r] = 0.f; }

    for (int kt = 0; kt < 32; ++kt) {
        const int k0 = kt * 64;
        __syncthreads();  // all waves done reading Ks/Vs of previous tile
        #pragma unroll
        for (int r = 0; r < 2; ++r) {
            int u = tid + 256 * r;       // 512 h8 units each
            int row = u >> 3, c8 = (u & 7) * 8;
            *(h8*)&Ks[row][c8] = *(const h8*)(k_ws + ((size_t)bh * S_LEN + k0 + row) * 64 + c8);
            *(h8*)&Vs[row][c8] = *(const h8*)(vt_ws + ((size_t)bh * 64 + row) * S_LEN + k0 + c8);
        }
        __syncthreads();

        // QK^T : S_tile[32 x 64] per wave
        f4 sacc[2][4] = {};
        #pragma unroll
        for (int ks = 0; ks < 2; ++ks) {
            h8 kf[4];
            #pragma unroll
            for (int j = 0; j < 4; ++j) kf[j] = *(const h8*)&Ks[j * 16 + l16][ks * 32 + g * 8];
            #pragma unroll
            for (int i = 0; i < 2; ++i)
                #pragma unroll
                for (int j = 0; j < 4; ++j)
                    sacc[i][j] = __builtin_amdgcn_mfma_f32_16x16x32_f16(qf[i][ks], kf[j], sacc[i][j], 0, 0, 0);
        }

        // mask + scale
        float sv[2][4][4];
        #pragma unroll
        for (int i = 0; i < 2; ++i)
            #pragma unroll
            for (int j = 0; j < 4; ++j)
                #pragma unroll
                for (int r = 0; r < 4; ++r) {
                    int rg = q0 + wave * 32 + i * 16 + g * 4 + r;
                    int cg = k0 + j * 16 + l16;
                    int mv = mask[((size_t)bh * S_LEN + rg) * S_LEN + cg];
                    float s = sacc[i][j][r] * 0.125f;
                    sv[i][j][r] = mv ? s : -1e4f;   // == s*m - 1e4*(1-m), m in {0,1}
                }

        // online softmax per row (i,r); row lives in the 16 lanes of quad g
        float al[2][4];
        #pragma unroll
        for (int i = 0; i < 2; ++i)
            #pragma unroll
            for (int r = 0; r < 4; ++r) {
                float mx = fmaxf(fmaxf(sv[i][0][r], sv[i][1][r]), fmaxf(sv[i][2][r], sv[i][3][r]));
                mx = fmaxf(mx, __shfl_xor(mx, 1));
                mx = fmaxf(mx, __shfl_xor(mx, 2));
                mx = fmaxf(mx, __shfl_xor(mx, 4));
                mx = fmaxf(mx, __shfl_xor(mx, 8));
                float mn = fmaxf(m_run[i][r], mx);
                float a  = __expf(m_run[i][r] - mn);   // exp(-inf)=0 first tile
                m_run[i][r] = mn;
                float sum = 0.f;
                #pragma unroll
                for (int j = 0; j < 4; ++j) {
                    float p = __expf(sv[i][j][r] - mn);
                    sv[i][j][r] = p;
                    sum += p;
                }
                sum += __shfl_xor(sum, 1);
                sum += __shfl_xor(sum, 2);
                sum += __shfl_xor(sum, 4);
                sum += __shfl_xor(sum, 8);
                l_run[i][r] = l_run[i][r] * a + sum;
                al[i][r] = a;
            }

        // rescale O accumulator
        #pragma unroll
        for (int i = 0; i < 2; ++i)
            #pragma unroll
            for (int jd = 0; jd < 4; ++jd)
                #pragma unroll
                for (int r = 0; r < 4; ++r)
                    oacc[i][jd][r] *= al[i][r];

        // P -> LDS (C-layout -> memory), wave-private rows, no barrier needed
        #pragma unroll
        for (int i = 0; i < 2; ++i)
            #pragma unroll
            for (int j = 0; j < 4; ++j)
                #pragma unroll
                for (int r = 0; r < 4; ++r)
                    Ps[wave * 32 + i * 16 + g * 4 + r][j * 16 + l16] = (_Float16)sv[i][j][r];

        // PV : O[32 x 64] per wave, contraction over 64 k-cols
        #pragma unroll
        for (int ks = 0; ks < 2; ++ks) {
            h8 pf[2], vf[4];
            #pragma unroll
            for (int i = 0; i < 2; ++i)  pf[i]  = *(const h8*)&Ps[wave * 32 + i * 16 + l16][ks * 32 + g * 8];
            #pragma unroll
            for (int jd = 0; jd < 4; ++jd) vf[jd] = *(const h8*)&Vs[jd * 16 + l16][ks * 32 + g * 8];
            #pragma unroll
            for (int i = 0; i < 2; ++i)
                #pragma unroll
                for (int jd = 0; jd < 4; ++jd)
                    oacc[i][jd] = __builtin_amdgcn_mfma_f32_16x16x32_f16(pf[i], vf[jd], oacc[i][jd], 0, 0, 0);
        }
    }

    // epilogue: normalize by l, write merged-head f16 [B,S,DM]
    const int b = bh >> 4, h = bh & 15;
    #pragma unroll
    for (int i = 0; i < 2; ++i)
        #pragma unroll
        for (int jd = 0; jd < 4; ++jd)
            #pragma unroll
            for (int r = 0; r < 4; ++r) {
                int row = q0 + wave * 32 + i * 16 + g * 4 + r;
                int d   = jd * 16 + l16;
                float val = oacc[i][jd][r] / l_run[i][r];
                o_ws[((size_t)b * S_LEN + row) * DM + h * 64 + d] = (_Float16)val;
            }
}

// ---------------------------------------------------------------------------
// Kernel 4: output projection. Y[m,n] = sum_k O[m,k]*Wy[n,k] + by[n] + by2[n]
// ---------------------------------------------------------------------------
__global__ __launch_bounds__(256, 2) void out_proj_kernel(
    const _Float16* __restrict__ A, const float* __restrict__ W,
    const float* __restrict__ b1, const float* __restrict__ b2,
    float* __restrict__ out)
{
    __shared__ _Float16 As[128][56];
    __shared__ _Float16 Bs[128][56];

    const int tid  = threadIdx.x;
    const int lane = tid & 63;
    const int wave = tid >> 6;
    const int l16  = lane & 15;
    const int g    = lane >> 4;
    const int wm   = (wave >> 1) * 64;
    const int wn   = (wave & 1) * 64;
    const int m0   = blockIdx.x * 128;
    const int n0   = blockIdx.y * 128;

    f4 acc[4][4] = {};

    for (int k0 = 0; k0 < 1024; k0 += 32) {
        __syncthreads();
        #pragma unroll
        for (int r = 0; r < 2; ++r) {     // A tile: 512 h8 units
            int u = tid + 256 * r;
            int row = u >> 2, c8 = (u & 3) * 8;
            *(h8*)&As[row][c8] = *(const h8*)(A + (size_t)(m0 + row) * 1024 + k0 + c8);
        }
        #pragma unroll
        for (int r = 0; r < 4; ++r) {     // B tile: fp32 -> f16
            int f = tid + 256 * r;
            int row = f >> 3, c4 = (f & 7) * 4;
            f4 xb = *(const f4*)(W + (size_t)(n0 + row) * 1024 + k0 + c4);
            Bs[row][c4 + 0] = (_Float16)xb.x; Bs[row][c4 + 1] = (_Float16)xb.y;
            Bs[row][c4 + 2] = (_Float16)xb.z; Bs[row][c4 + 3] = (_Float16)xb.w;
        }
        __syncthreads();

        h8 af[4], bf[4];
        #pragma unroll
        for (int i = 0; i < 4; ++i) af[i] = *(const h8*)&As[wm + i * 16 + l16][g * 8];
        #pragma unroll
        for (int j = 0; j < 4; ++j) bf[j] = *(const h8*)&Bs[wn + j * 16 + l16][g * 8];
        #pragma unroll
        for (int i = 0; i < 4; ++i)
            #pragma unroll
            for (int j = 0; j < 4; ++j)
                acc[i][j] = __builtin_amdgcn_mfma_f32_16x16x32_f16(af[i], bf[j], acc[i][j], 0, 0, 0);
    }

    #pragma unroll
    for (int i = 0; i < 4; ++i)
        #pragma unroll
        for (int j = 0; j < 4; ++j)
            #pragma unroll
            for (int r = 0; r < 4; ++r) {
                int gm = m0 + wm + i * 16 + g * 4 + r;
                int gn = n0 + wn + j * 16 + l16;
                out[(size_t)gm * 1024 + gn] = acc[i][j][r] + b1[gn] + b2[gn];
            }
}

// ---------------------------------------------------------------------------
extern "C" void kernel_launch(void* const* d_in, const int* in_sizes, int n_in,
                              void* d_out, int out_size, void* d_ws, size_t ws_size,
                              hipStream_t stream)
{
    (void)in_sizes; (void)n_in; (void)out_size; (void)ws_size;
    const float* queries = (const float*)d_in[0];
    const float* keys    = (const float*)d_in[1];
    const float* values  = (const float*)d_in[2];
    const int*   mask    = (const int*)d_in[3];
    const float* Wq  = (const float*)d_in[4];
    const float* bq  = (const float*)d_in[5];
    const float* Wk  = (const float*)d_in[6];
    const float* bk  = (const float*)d_in[7];
    const float* Wv  = (const float*)d_in[8];
    const float* bv  = (const float*)d_in[9];
    const float* Wy  = (const float*)d_in[10];
    const float* by  = (const float*)d_in[11];
    const float* bq2 = (const float*)d_in[12];
    const float* bk2 = (const float*)d_in[13];
    const float* bv2 = (const float*)d_in[14];
    const float* by2 = (const float*)d_in[15];
    float* out = (float*)d_out;

    char* ws = (char*)d_ws;
    const size_t MB8 = (size_t)8 * 1024 * 1024;
    _Float16* q_ws  = (_Float16*)(ws);
    _Float16* k_ws  = (_Float16*)(ws + 1 * MB8);
    _Float16* v_ws  = (_Float16*)(ws + 2 * MB8);
    _Float16* vt_ws = (_Float16*)(ws + 3 * MB8);
    _Float16* o_ws  = (_Float16*)(ws + 4 * MB8);

    qkv_proj_kernel<<<dim3(32, 8, 3), 256, 0, stream>>>(
        queries, keys, values, Wq, Wk, Wv, bq, bk, bv, bq2, bk2, bv2,
        q_ws, k_ws, v_ws);
    transpose_v_kernel<<<dim3(32, 32), 256, 0, stream>>>(v_ws, vt_ws);
    attn_kernel<<<dim3(16, 32), 256, 0, stream>>>(q_ws, k_ws, vt_ws, mask, o_ws);
    out_proj_kernel<<<dim3(32, 8), 256, 0, stream>>>(o_ws, Wy, by, by2, out);
}